// Round 1
// 623.178 us; speedup vs baseline: 1.1050x; 1.1050x over previous
//
#include <hip/hip_runtime.h>

// Fused Conv1d(k=3,pad=1) + BN(inference) + 4-step LIF + residual.
// x: (L=2048, TB=128, D=128) f32. conv_w: (D,D,3). out: (L,TB,D) f32.
//
// R3: output-channel blocking ob=2. Each thread computes 2 o's x 16 l's.
// Broadcast xs reads (the saturated LDS pipe) now feed 24 FMAs each
// instead of 12; per-CU ds_read_b128 count drops ~43%. Accumulation
// order per o is bit-identical to R2 (absmax must stay 0.0).

constexpr int L   = 2048;
constexpr int NTB = 128;
constexpr int D   = 128;
constexpr int T   = 4;
constexpr int LT  = 64;        // l-tile per block (4 wave-halves x JT)
constexpr int NP  = LT + 2;    // 66 staged positions (halo)
constexpr int JT  = 16;        // l-positions per thread
constexpr int IT  = 8;         // input channels per LDS weight stage
constexpr int WROW = 52;       // paired w row: o0 @ [0,24), pad, o1 @ [28,52)

__global__ __launch_bounds__(256, 3)
void snn_conv_lif(const float* __restrict__ x, const float* __restrict__ w,
                  const float* __restrict__ gamma, const float* __restrict__ beta,
                  const float* __restrict__ mean, const float* __restrict__ var,
                  float* __restrict__ out) {
    __shared__ float xs[NP * D];      // 33792 B
    __shared__ float ws[64 * WROW];   // 13312 B  (total 47104 B -> 3 blocks/CU)

    const int tid = threadIdx.x;
    const int b   = blockIdx.x & 31;
    const int lt  = blockIdx.x >> 5;
    const int l0  = lt * LT;
    const int q   = tid & 63;          // o-pair index: o = 2q, 2q+1
    const int lh  = tid >> 6;          // wave index (wave-uniform!) -> xs stays broadcast
    const int p0  = lh * JT;

    const int o0 = 2 * q, o1 = o0 + 1;
    // BN folded: y = conv*sc + bi
    const float sc0 = gamma[o0] / sqrtf(var[o0] + 1e-5f);
    const float bi0 = beta[o0] - mean[o0] * sc0;
    const float sc1 = gamma[o1] / sqrtf(var[o1] + 1e-5f);
    const float bi1 = beta[o1] - mean[o1] * sc1;

    float v0[JT], v1[JT];
    #pragma unroll
    for (int j = 0; j < JT; ++j) { v0[j] = 0.f; v1[j] = 0.f; }

    #pragma unroll 1
    for (int t = 0; t < T; ++t) {
        const int n = t * 32 + b;
        __syncthreads();   // protect xs from previous epilogue readers
        // ---- stage x[l0-1 .. l0+LT][n][:] into xs[pos][i] ----
        for (int idx = tid; idx < NP * 32; idx += 256) {
            const int p = idx >> 5, c = idx & 31;
            const int l = l0 - 1 + p;
            float4 val = make_float4(0.f, 0.f, 0.f, 0.f);
            if (l >= 0 && l < L)
                val = ((const float4*)x)[l * (NTB * D / 4) + n * (D / 4) + c];
            ((float4*)xs)[p * (D / 4) + c] = val;
        }

        float a0[JT], a1[JT];
        #pragma unroll
        for (int j = 0; j < JT; ++j) { a0[j] = 0.f; a1[j] = 0.f; }

        #pragma unroll 1
        for (int it = 0; it < D / IT; ++it) {
            __syncthreads();  // ws reuse guard (also covers xs ready at it==0)
            // ---- stage weight i-tile, paired rows: 64 q-rows x 12 float4 ----
            for (int idx = tid; idx < 768; idx += 256) {
                const int qq = idx / 12;
                const int r  = idx - qq * 12;
                const int oo = (r >= 6) ? 1 : 0;
                const int c  = r - 6 * oo;
                float4 wv = ((const float4*)(w + (2 * qq + oo) * (D * 3) + it * (IT * 3)))[c];
                *((float4*)(ws + qq * WROW + oo * 28 + c * 4)) = wv;
            }
            __syncthreads();

            const float* wrow = ws + q * WROW;
            #pragma unroll
            for (int i4 = 0; i4 < IT / 4; ++i4) {
                const float4 wa0 = *((const float4*)(wrow + i4 * 12));
                const float4 wa1 = *((const float4*)(wrow + i4 * 12 + 4));
                const float4 wa2 = *((const float4*)(wrow + i4 * 12 + 8));
                const float4 wb0 = *((const float4*)(wrow + 28 + i4 * 12));
                const float4 wb1 = *((const float4*)(wrow + 28 + i4 * 12 + 4));
                const float4 wb2 = *((const float4*)(wrow + 28 + i4 * 12 + 8));
                // w[i_loc*3 + k] for 4 i's, per output channel
                const float wA[12] = {wa0.x, wa0.y, wa0.z, wa0.w,
                                      wa1.x, wa1.y, wa1.z, wa1.w,
                                      wa2.x, wa2.y, wa2.z, wa2.w};
                const float wB[12] = {wb0.x, wb0.y, wb0.z, wb0.w,
                                      wb1.x, wb1.y, wb1.z, wb1.w,
                                      wb2.x, wb2.y, wb2.z, wb2.w};
                const float4* xcol = (const float4*)xs + (it * 2 + i4);
                float4 xa = xcol[(p0 + 0) * (D / 4)];
                float4 xb = xcol[(p0 + 1) * (D / 4)];
                #pragma unroll
                for (int j = 0; j < JT; ++j) {
                    const float4 xc = xcol[(p0 + j + 2) * (D / 4)];
                    float s0 = a0[j];
                    float s1 = a1[j];
                    s0 = fmaf(xa.x, wA[0], s0);   s1 = fmaf(xa.x, wB[0], s1);   // k=0,i+0
                    s0 = fmaf(xa.y, wA[3], s0);   s1 = fmaf(xa.y, wB[3], s1);   // k=0,i+1
                    s0 = fmaf(xa.z, wA[6], s0);   s1 = fmaf(xa.z, wB[6], s1);
                    s0 = fmaf(xa.w, wA[9], s0);   s1 = fmaf(xa.w, wB[9], s1);
                    s0 = fmaf(xb.x, wA[1], s0);   s1 = fmaf(xb.x, wB[1], s1);   // k=1
                    s0 = fmaf(xb.y, wA[4], s0);   s1 = fmaf(xb.y, wB[4], s1);
                    s0 = fmaf(xb.z, wA[7], s0);   s1 = fmaf(xb.z, wB[7], s1);
                    s0 = fmaf(xb.w, wA[10], s0);  s1 = fmaf(xb.w, wB[10], s1);
                    s0 = fmaf(xc.x, wA[2], s0);   s1 = fmaf(xc.x, wB[2], s1);   // k=2
                    s0 = fmaf(xc.y, wA[5], s0);   s1 = fmaf(xc.y, wB[5], s1);
                    s0 = fmaf(xc.z, wA[8], s0);   s1 = fmaf(xc.z, wB[8], s1);
                    s0 = fmaf(xc.w, wA[11], s0);  s1 = fmaf(xc.w, wB[11], s1);
                    a0[j] = s0; a1[j] = s1;
                    xa = xb; xb = xc;
                }
            }
        }

        // ---- BN + LIF step + residual + store (float2 over the o-pair) ----
        #pragma unroll
        for (int j = 0; j < JT; ++j) {
            const float y0 = fmaf(a0[j], sc0, bi0);
            const float y1 = fmaf(a1[j], sc1, bi1);
            const float h0 = 0.5f * (v0[j] + y0);      // v + (y - v)/tau, tau=2
            const float h1 = 0.5f * (v1[j] + y1);
            const bool f0 = (h0 >= 1.0f);
            const bool f1 = (h1 >= 1.0f);
            v0[j] = f0 ? 0.0f : h0;                    // hard reset
            v1[j] = f1 ? 0.0f : h1;
            const int l = l0 + p0 + j;
            const float2 res = ((const float2*)xs)[(p0 + j + 1) * (D / 2) + q];
            float2 ov;
            ov.x = res.x + (f0 ? 1.0f : 0.0f);
            ov.y = res.y + (f1 ? 1.0f : 0.0f);
            ((float2*)out)[(l * NTB + n) * (D / 2) + q] = ov;
        }
    }
}

extern "C" void kernel_launch(void* const* d_in, const int* in_sizes, int n_in,
                              void* d_out, int out_size, void* d_ws, size_t ws_size,
                              hipStream_t stream) {
    const float* x     = (const float*)d_in[0];
    const float* w     = (const float*)d_in[1];
    const float* gamma = (const float*)d_in[2];
    const float* beta  = (const float*)d_in[3];
    const float* mean  = (const float*)d_in[4];
    const float* var   = (const float*)d_in[5];
    float* out = (float*)d_out;

    dim3 grid((L / LT) * 32);   // 32 l-tiles x 32 b values = 1024 blocks
    dim3 block(256);
    snn_conv_lif<<<grid, block, 0, stream>>>(x, w, gamma, beta, mean, var, out);
}